// Round 1
// baseline (2038.644 us; speedup 1.0000x reference)
//
#include <hip/hip_runtime.h>
#include <stdint.h>

#define ALPHA 0.1f
#define NN 20000
#define DF 768
#define NE 200000
#define NB 64
#define TSEQ 128
#define SF 128
#define HS 512
#define NCLS 14

typedef __attribute__((ext_vector_type(8))) short short8;
typedef __attribute__((ext_vector_type(4))) float f32x4;

// ---------------- workspace layout (bytes) ----------------
#define OFF_DEG     0u           // int[20000]
#define OFF_CSRC    80000u       // int[20000]
#define OFF_CNTB    160000u      // int[64]
#define OFF_BAR     160256u      // u32[16*16] barrier counters (64B stride)
#define OFF_FLAG    161280u      // int[1] : 1 if indices are int64
#define ZERO_INTS   40324u       // zero [0, 161296)
#define OFF_ROWPTR  161536u      // int[20001]
#define OFF_CURSOR  241664u      // int[20000]
#define OFF_DINV    321664u      // float[20000]
#define OFF_COL     401664u      // int[200000]
#define OFF_WGT     1201664u     // float[200000]
#define OFF_V0      2001920u     // float[20000*64]
#define OFF_V1      7121920u     // float[20000*64]
#define OFF_HBUF    12241920u    // bf16 [2][2][64][512]
#define OFF_YSEQ    12504064u    // float[64*1024]
#define OFF_SH1     12766208u    // float[64*512]
#define OFF_SH2     12897280u    // float[64*256]
#define OFF_PART    12962816u    // float[32][64][768]
#define OFF_POOL    19254272u    // float[64*768]
#define OFF_GH1     19450880u    // float[64*384]
#define OFF_GH2     19549184u    // float[64*192]

__device__ __forceinline__ unsigned short f2b(float f) {
  union { float f; unsigned u; } v; v.f = f;
  unsigned u = v.u;
  return (unsigned short)((u + 0x7FFFu + ((u >> 16) & 1u)) >> 16);
}

__device__ __forceinline__ int idx_at(const int* p, long long i, int mode64) {
  return mode64 ? p[2*i] : p[i];   // little-endian low word
}

// ---------------- small utility kernels ----------------
__global__ void zero_ints_kernel(int* p, int n) {
  int i = blockIdx.x * blockDim.x + threadIdx.x;
  if (i < n) p[i] = 0;
}

__global__ void detect_i64_kernel(const int* e, int* flag) {
  if (threadIdx.x == 0 && blockIdx.x == 0) {
    int all0 = 1;
    for (int i = 0; i < 256; ++i) if (e[2*i + 1] != 0) { all0 = 0; break; }
    *flag = all0;
  }
}

__global__ void hist_kernel(const int* e, const int* batch, int* deg, int* csrc,
                            int* cntb, const int* flag) {
  int i = blockIdx.x * blockDim.x + threadIdx.x;
  int m = *flag;
  if (i < NE) {
    int s = idx_at(e, i, m);
    int d = idx_at(e, (long long)NE + i, m);
    atomicAdd(&csrc[s], 1);
    atomicAdd(&deg[d], 1);
  }
  if (i < NN) atomicAdd(&cntb[idx_at(batch, i, m)], 1);
}

__global__ void dinv_kernel(const int* deg, float* dinv) {
  int i = blockIdx.x * blockDim.x + threadIdx.x;
  if (i < NN) dinv[i] = rsqrtf((float)(deg[i] + 1));   // +1 self loop, >=1
}

__global__ void scan_kernel(const int* cnt, int* row_ptr, int* cursor) {
  __shared__ int sA[1024], sB[1024];
  int tid = threadIdx.x;
  int carry = 0;
  const int nch = (NN + 1023) / 1024;
  for (int c = 0; c < nch; ++c) {
    int i = c * 1024 + tid;
    int v = (i < NN) ? cnt[i] : 0;
    sA[tid] = v;
    __syncthreads();
    int* src = sA; int* dst = sB;
    for (int off = 1; off < 1024; off <<= 1) {
      dst[tid] = src[tid] + (tid >= off ? src[tid - off] : 0);
      __syncthreads();
      int* t = src; src = dst; dst = t;
    }
    if (i < NN) { int ex = carry + src[tid] - v; row_ptr[i] = ex; cursor[i] = ex; }
    carry += src[1023];
    __syncthreads();
  }
  if (tid == 0) row_ptr[NN] = carry;
}

__global__ void fill_kernel(const int* e, const float* dinv, int* cursor,
                            int* colA, float* wgt, const int* flag) {
  int i = blockIdx.x * blockDim.x + threadIdx.x;
  if (i >= NE) return;
  int m = *flag;
  int s = idx_at(e, i, m);
  int d = idx_at(e, (long long)NE + i, m);
  int pos = atomicAdd(&cursor[s], 1);
  colA[pos] = d;
  wgt[pos] = dinv[s] * dinv[d];
}

__global__ void v0init_kernel(const int* batch, float* v0, const int* flag) {
  int i = blockIdx.x * blockDim.x + threadIdx.x;
  if (i >= NN * 64) return;
  int n = i >> 6, b = i & 63;
  v0[i] = (idx_at(batch, n, *flag) == b) ? 1.0f : 0.0f;
}

// one wave per node, lane = graph id (64 == wave width)
__global__ void hop_kernel(const float* __restrict__ vin, float* __restrict__ vout,
                           const int* __restrict__ row_ptr, const int* __restrict__ colA,
                           const float* __restrict__ wgt, const float* __restrict__ dinv,
                           const int* __restrict__ batch, const int* __restrict__ flag) {
  int wid = (blockIdx.x * blockDim.x + threadIdx.x) >> 6;
  int lane = threadIdx.x & 63;
  if (wid >= NN) return;
  float di = dinv[wid];
  float acc = di * di * vin[wid * 64 + lane];
  int e0 = row_ptr[wid], e1 = row_ptr[wid + 1];
  int e = e0;
  for (; e + 1 < e1; e += 2) {
    int c0 = colA[e], c1 = colA[e + 1];
    float w0 = wgt[e], w1 = wgt[e + 1];
    acc += w0 * vin[c0 * 64 + lane] + w1 * vin[c1 * 64 + lane];
  }
  if (e < e1) acc += wgt[e] * vin[colA[e] * 64 + lane];
  float y0 = (idx_at(batch, wid, *flag) == lane) ? ALPHA : 0.0f;
  vout[wid * 64 + lane] = (1.0f - ALPHA) * acc + y0;
}

// pooled_unnorm partials: 48 f-tiles x 32 node-chunks, lane = graph id
__global__ void spmm_kernel(const float* __restrict__ S, const float* __restrict__ x,
                            float* __restrict__ partial) {
  int wid = (blockIdx.x * blockDim.x + threadIdx.x) >> 6;   // 1536 waves
  int lane = threadIdx.x & 63;
  int ft = wid % 48, ch = wid / 48;
  if (ch >= 32) return;
  int f0 = ft * 16;
  int n0 = ch * 625, n1 = n0 + 625;
  float acc[16];
#pragma unroll
  for (int f = 0; f < 16; ++f) acc[f] = 0.0f;
  for (int n = n0; n < n1; ++n) {
    float sv = S[n * 64 + lane];
    const float* xr = x + (size_t)n * DF + f0;
#pragma unroll
    for (int f = 0; f < 16; ++f) acc[f] += sv * xr[f];
  }
  float* pr = partial + ((size_t)(ch * 64 + lane)) * DF + f0;
#pragma unroll
  for (int f = 0; f < 16; ++f) pr[f] = acc[f];
}

__global__ void reduce_pool_kernel(const float* __restrict__ partial, const int* __restrict__ cntb,
                                   float* __restrict__ pooled) {
  int i = blockIdx.x * blockDim.x + threadIdx.x;
  if (i >= 64 * DF) return;
  int b = i / DF, f = i - b * DF;
  float s = 0.0f;
  for (int c = 0; c < 32; ++c) s += partial[((size_t)(c * 64 + b)) * DF + f];
  int cnt = cntb[b]; if (cnt < 1) cnt = 1;
  pooled[i] = s / (float)cnt;
}

// C[M,N] = act(A[M,K] @ W[N,K]^T + bias), optionally accumulate into C
__global__ void mlp_layer_kernel(const float* __restrict__ A, const float* __restrict__ W,
                                 const float* __restrict__ bias, float* __restrict__ C,
                                 int M, int N, int K, int relu, int accum) {
  int i = blockIdx.x * blockDim.x + threadIdx.x;
  if (i >= M * N) return;
  int mrow = i / N, n = i - mrow * N;
  float acc = bias[n];
  const float4* a4 = (const float4*)(A + (size_t)mrow * K);
  const float4* w4 = (const float4*)(W + (size_t)n * K);
  int k4 = K >> 2;
#pragma unroll 4
  for (int k = 0; k < k4; ++k) {
    float4 av = a4[k], wv = w4[k];
    acc += av.x * wv.x + av.y * wv.y + av.z * wv.z + av.w * wv.w;
  }
  if (relu) acc = fmaxf(acc, 0.0f);
  if (accum) C[i] += acc; else C[i] = acc;
}

// ---------------- GRU recurrent kernel ----------------
// grid 256 blocks x 384 thr. 16 groups x 16 ranks. group: dir=g>>3, seqs (g&7)*8..+8
// rank owns gate columns j0=rank*32 .. +32 (for r,z,n). Weights stationary in LDS (bf16).
// LDS: W1[96][672]: rows 0..63 = [Whh_r|Wih_r ; Whh_z|Wih_z] (K=640), rows 64..95 = Whh_n (K=512)
//      W2[32][136]: Wih_n (K=128)
//      hl[16][672]: rows 0..7 = [h | x_t] bf16, rows 8..15 scratch (gh staging floats)
#define GRU_LDS_BYTES 159232

__global__ __launch_bounds__(384, 1) void gru_kernel(
    const float* __restrict__ seq,
    const float* __restrict__ wih_f, const float* __restrict__ whh_f,
    const float* __restrict__ bih_f, const float* __restrict__ bhh_f,
    const float* __restrict__ wih_b, const float* __restrict__ whh_b,
    const float* __restrict__ bih_b, const float* __restrict__ bhh_b,
    unsigned* __restrict__ barrier_ws, unsigned short* __restrict__ hbuf,
    float* __restrict__ y_seq) {
  extern __shared__ char smem_raw[];
  unsigned short* W1 = (unsigned short*)smem_raw;       // 96*672
  unsigned short* W2 = W1 + 96 * 672;                   // 32*136
  unsigned short* hl = W2 + 32 * 136;                   // 16*672
  float* ghs = (float*)(hl + 8 * 672);                  // [128][8]

  const int tid = threadIdx.x;
  const int wave = tid >> 6, lane = tid & 63;
  const int g = blockIdx.x >> 4, rk = blockIdx.x & 15;
  const int d = g >> 3;
  const int seqbase = (g & 7) * 8;
  const int j0 = rk * 32;

  const float* wih = d ? wih_b : wih_f;
  const float* whh = d ? whh_b : whh_f;
  const float* bih = d ? bih_b : bih_f;
  const float* bhh = d ? bhh_b : bhh_f;

  // load stationary weights -> LDS (fp32 -> bf16)
  for (int idx = tid; idx < 96 * 640; idx += 384) {
    int row = idx / 640, c = idx - row * 640;
    float val;
    if (row < 64) {
      int gcol = (row < 32) ? (j0 + row) : (512 + j0 + row - 32);
      val = (c < 512) ? whh[gcol * 512 + c] : wih[gcol * 128 + (c - 512)];
    } else {
      int gcol = 1024 + j0 + (row - 64);
      val = (c < 512) ? whh[gcol * 512 + c] : 0.0f;
    }
    W1[row * 672 + c] = f2b(val);
  }
  for (int idx = tid; idx < 32 * 128; idx += 384) {
    int row = idx >> 7, c = idx & 127;
    W2[row * 136 + c] = f2b(wih[(1024 + j0 + row) * 128 + c]);
  }
  for (int idx = tid; idx < 8 * 512; idx += 384) {   // h(0) = 0
    int s = idx >> 9, c = idx & 511;
    hl[s * 672 + c] = 0;
  }

  float bias_r = 0, bias_z = 0, bihn = 0, bhhn = 0;
  float hprev = 0, msum = 0, mx = -1e30f;
  int seq_i = 0, col_i = 0;
  if (tid < 256) {
    seq_i = tid >> 5; col_i = tid & 31;
    bias_r = bih[j0 + col_i] + bhh[j0 + col_i];
    bias_z = bih[512 + j0 + col_i] + bhh[512 + j0 + col_i];
    bihn = bih[1024 + j0 + col_i];
    bhhn = bhh[1024 + j0 + col_i];
  }
  unsigned* cnt = barrier_ws + g * 16;   // 64B stride per group
  __syncthreads();

  const int quad = lane >> 4, l15 = lane & 15;

  for (int t = 0; t < 128; ++t) {
    int tt = d ? (127 - t) : t;
    // stage x_t into hl cols 512..639
    for (int i = 0; i < 3; ++i) {
      int flat = tid + 384 * i;
      if (flat < 1024) {
        int s = flat >> 7, k = flat & 127;
        hl[s * 672 + 512 + k] = f2b(seq[(size_t)(seqbase + s) * (TSEQ * SF) + tt * SF + k]);
      }
    }
    __syncthreads();

    f32x4 acc0 = {0, 0, 0, 0}, acc1 = {0, 0, 0, 0};
    const unsigned short* arow = hl + l15 * 672 + quad * 8;
    if (wave < 4) {        // fused r,z gates: K = 640 (h | x)
      const unsigned short* brow = W1 + (wave * 16 + l15) * 672 + quad * 8;
#pragma unroll
      for (int kc = 0; kc < 20; ++kc) {
        short8 a = *(const short8*)(arow + kc * 32);
        short8 b = *(const short8*)(brow + kc * 32);
        acc0 = __builtin_amdgcn_mfma_f32_16x16x32_bf16(a, b, acc0, 0, 0, 0);
      }
    } else {               // gh_n (K=512) and gi_n (K=128) separately
      const unsigned short* brow = W1 + (64 + (wave - 4) * 16 + l15) * 672 + quad * 8;
#pragma unroll
      for (int kc = 0; kc < 16; ++kc) {
        short8 a = *(const short8*)(arow + kc * 32);
        short8 b = *(const short8*)(brow + kc * 32);
        acc0 = __builtin_amdgcn_mfma_f32_16x16x32_bf16(a, b, acc0, 0, 0, 0);
      }
      const unsigned short* brow2 = W2 + ((wave - 4) * 16 + l15) * 136 + quad * 8;
#pragma unroll
      for (int kc = 0; kc < 4; ++kc) {
        short8 a = *(const short8*)(arow + 512 + kc * 32);
        short8 b = *(const short8*)(brow2 + kc * 32);
        acc1 = __builtin_amdgcn_mfma_f32_16x16x32_bf16(a, b, acc1, 0, 0, 0);
      }
    }
    __syncthreads();   // GEMM done; hl rows 8..15 reusable as gh staging
    if (wave < 4) {
      int row = wave * 16 + l15;
#pragma unroll
      for (int rr = 0; rr < 4; ++rr) {
        int m = quad * 4 + rr;
        if (m < 8) ghs[row * 8 + m] = acc0[rr];
      }
    } else {
      int rowg = 64 + (wave - 4) * 16 + l15;
      int rowi = 96 + (wave - 4) * 16 + l15;
#pragma unroll
      for (int rr = 0; rr < 4; ++rr) {
        int m = quad * 4 + rr;
        if (m < 8) { ghs[rowg * 8 + m] = acc0[rr]; ghs[rowi * 8 + m] = acc1[rr]; }
      }
    }
    __syncthreads();

    if (tid < 256) {   // gates for (seq_i, col_i)
      float gr = ghs[col_i * 8 + seq_i];
      float gz = ghs[(32 + col_i) * 8 + seq_i];
      float gn = ghs[(64 + col_i) * 8 + seq_i];
      float gi = ghs[(96 + col_i) * 8 + seq_i];
      float r = 1.0f / (1.0f + __expf(-(gr + bias_r)));
      float z = 1.0f / (1.0f + __expf(-(gz + bias_z)));
      float narg = gi + bihn + r * (gn + bhhn);
      float e2 = __expf(-2.0f * fabsf(narg));
      float nt = (1.0f - e2) / (1.0f + e2);
      nt = (narg < 0.0f) ? -nt : nt;
      float h2 = (1.0f - z) * nt + z * hprev;
      hprev = h2; msum += h2; mx = fmaxf(mx, h2);
      float other = __shfl_down(h2, 1);
      if ((tid & 1) == 0) {
        unsigned pk = (unsigned)f2b(h2) | ((unsigned)f2b(other) << 16);
        unsigned* dst = (unsigned*)hbuf +
            (((( (t & 1) * 2 + d) * 64 + seqbase + seq_i) * 256) + ((j0 + col_i) >> 1));
        __hip_atomic_store(dst, pk, __ATOMIC_RELAXED, __HIP_MEMORY_SCOPE_AGENT);
      }
    }
    __syncthreads();
    if (tid == 0) {    // group barrier (16 ranks)
      __hip_atomic_fetch_add(cnt, 1u, __ATOMIC_ACQ_REL, __HIP_MEMORY_SCOPE_AGENT);
      unsigned target = 16u * (unsigned)(t + 1);
      int guard = 0;
      while (__hip_atomic_load(cnt, __ATOMIC_ACQUIRE, __HIP_MEMORY_SCOPE_AGENT) < target) {
        __builtin_amdgcn_s_sleep(2);
        if (++guard > (1 << 24)) break;   // safety: wrong answer beats a hang
      }
    }
    __syncthreads();
    {   // gather full h(t+1) for the group (bf16, 8 seq x 512)
      const unsigned long long* hb64 = (const unsigned long long*)hbuf;
      for (int i = 0; i < 3; ++i) {
        int flat = tid + 384 * i;
        if (flat < 1024) {
          int s = flat >> 7, idx = flat & 127;
          unsigned long long v = __hip_atomic_load(
              hb64 + ((((t & 1) * 2 + d) * 64 + seqbase + s) * 128 + idx),
              __ATOMIC_RELAXED, __HIP_MEMORY_SCOPE_AGENT);
          *(unsigned long long*)(hl + s * 672 + idx * 4) = v;
        }
      }
    }
    // next iteration's post-stage __syncthreads guards hl before GEMM
  }

  if (tid < 256) {   // seq1 + seq2 = mean + max over T
    y_seq[(size_t)(seqbase + seq_i) * 1024 + d * 512 + j0 + col_i] =
        msum * (1.0f / 128.0f) + mx;
  }
}

// ---------------- launcher ----------------
extern "C" void kernel_launch(void* const* d_in, const int* in_sizes, int n_in,
                              void* d_out, int out_size, void* d_ws, size_t ws_size,
                              hipStream_t stream) {
  const float* x      = (const float*)d_in[0];
  const int*   eidx   = (const int*)d_in[1];
  const float* seq    = (const float*)d_in[2];
  const int*   batch  = (const int*)d_in[3];
  const float* wih_f  = (const float*)d_in[4];
  const float* whh_f  = (const float*)d_in[5];
  const float* bih_f  = (const float*)d_in[6];
  const float* bhh_f  = (const float*)d_in[7];
  const float* wih_b  = (const float*)d_in[8];
  const float* whh_b  = (const float*)d_in[9];
  const float* bih_b  = (const float*)d_in[10];
  const float* bhh_b  = (const float*)d_in[11];
  const float* mg_w0  = (const float*)d_in[12];
  const float* mg_b0  = (const float*)d_in[13];
  const float* mg_w1  = (const float*)d_in[14];
  const float* mg_b1  = (const float*)d_in[15];
  const float* mg_w2  = (const float*)d_in[16];
  const float* mg_b2  = (const float*)d_in[17];
  const float* ms_w0  = (const float*)d_in[18];
  const float* ms_b0  = (const float*)d_in[19];
  const float* ms_w1  = (const float*)d_in[20];
  const float* ms_b1  = (const float*)d_in[21];
  const float* ms_w2  = (const float*)d_in[22];
  const float* ms_b2  = (const float*)d_in[23];
  float* out = (float*)d_out;
  char* ws = (char*)d_ws;

  int*   deg     = (int*)(ws + OFF_DEG);
  int*   csrc    = (int*)(ws + OFF_CSRC);
  int*   cntb    = (int*)(ws + OFF_CNTB);
  unsigned* bar  = (unsigned*)(ws + OFF_BAR);
  int*   flag    = (int*)(ws + OFF_FLAG);
  int*   row_ptr = (int*)(ws + OFF_ROWPTR);
  int*   cursor  = (int*)(ws + OFF_CURSOR);
  float* dinv    = (float*)(ws + OFF_DINV);
  int*   colA    = (int*)(ws + OFF_COL);
  float* wgtA    = (float*)(ws + OFF_WGT);
  float* V0      = (float*)(ws + OFF_V0);
  float* V1      = (float*)(ws + OFF_V1);
  unsigned short* hbuf = (unsigned short*)(ws + OFF_HBUF);
  float* y_seq   = (float*)(ws + OFF_YSEQ);
  float* sh1     = (float*)(ws + OFF_SH1);
  float* sh2     = (float*)(ws + OFF_SH2);
  float* part    = (float*)(ws + OFF_PART);
  float* pooled  = (float*)(ws + OFF_POOL);
  float* gh1     = (float*)(ws + OFF_GH1);
  float* gh2     = (float*)(ws + OFF_GH2);

  hipFuncSetAttribute((const void*)gru_kernel,
                      hipFuncAttributeMaxDynamicSharedMemorySize, GRU_LDS_BYTES);

  // ---- graph prep (CSR for A^T, degrees, batch counts) ----
  zero_ints_kernel<<<(ZERO_INTS + 255) / 256, 256, 0, stream>>>((int*)ws, (int)ZERO_INTS);
  detect_i64_kernel<<<1, 64, 0, stream>>>(eidx, flag);
  hist_kernel<<<(NE + 255) / 256, 256, 0, stream>>>(eidx, batch, deg, csrc, cntb, flag);
  dinv_kernel<<<(NN + 255) / 256, 256, 0, stream>>>(deg, dinv);
  scan_kernel<<<1, 1024, 0, stream>>>(csrc, row_ptr, cursor);
  fill_kernel<<<(NE + 255) / 256, 256, 0, stream>>>(eidx, dinv, cursor, colA, wgtA, flag);
  v0init_kernel<<<(NN * 64 + 255) / 256, 256, 0, stream>>>(batch, V0, flag);

  // ---- APPNP, transposed: propagate 64-wide pooling coefficients ----
  for (int h = 0; h < 16; ++h) {
    const float* vin = (h & 1) ? V1 : V0;
    float* vout = (h & 1) ? V0 : V1;
    hop_kernel<<<(NN * 64 + 255) / 256, 256, 0, stream>>>(vin, vout, row_ptr, colA,
                                                          wgtA, dinv, batch, flag);
  }

  // ---- BiGRU (fused gi + recurrent + pooling) ----
  gru_kernel<<<256, 384, GRU_LDS_BYTES, stream>>>(
      seq, wih_f, whh_f, bih_f, bhh_f, wih_b, whh_b, bih_b, bhh_b, bar, hbuf, y_seq);

  // ---- seq MLP: 1024 -> 512 -> 256 -> 14 (writes d_out) ----
  mlp_layer_kernel<<<(64 * 512 + 255) / 256, 256, 0, stream>>>(y_seq, ms_w0, ms_b0, sh1,
                                                               64, 512, 1024, 1, 0);
  mlp_layer_kernel<<<(64 * 256 + 255) / 256, 256, 0, stream>>>(sh1, ms_w1, ms_b1, sh2,
                                                               64, 256, 512, 1, 0);
  mlp_layer_kernel<<<(64 * NCLS + 255) / 256, 256, 0, stream>>>(sh2, ms_w2, ms_b2, out,
                                                                64, NCLS, 256, 0, 0);

  // ---- pooled = (S^T x) / cnt ; after 16 hops result is in V0 ----
  spmm_kernel<<<(1536 * 64) / 256, 256, 0, stream>>>(V0, x, part);
  reduce_pool_kernel<<<(64 * DF + 255) / 256, 256, 0, stream>>>(part, cntb, pooled);

  // ---- graph MLP: 768 -> 384 -> 192 -> 14 (accumulates into d_out) ----
  mlp_layer_kernel<<<(64 * 384 + 255) / 256, 256, 0, stream>>>(pooled, mg_w0, mg_b0, gh1,
                                                               64, 384, 768, 1, 0);
  mlp_layer_kernel<<<(64 * 192 + 255) / 256, 256, 0, stream>>>(gh1, mg_w1, mg_b1, gh2,
                                                               64, 192, 384, 1, 0);
  mlp_layer_kernel<<<(64 * NCLS + 255) / 256, 256, 0, stream>>>(gh2, mg_w2, mg_b2, out,
                                                                64, NCLS, 192, 0, 1);
  (void)in_sizes; (void)n_in; (void)out_size; (void)ws_size;
}